// Round 2
// baseline (439.715 us; speedup 1.0000x reference)
//
#include <hip/hip_runtime.h>

// Fused 7-layer 1x1-conv chain: L1-L3 (128->64->32->16) via bf16 MFMA 16x16x32
// (fp32 accumulate), L4-L7 (16->8->4->2->1) as per-lane fp32 VALU tail.
// One wave = 64 pixels (4 N-tiles of 16). x B-frags load straight from global in
// fragment layout (no LDS staging). h1/h2 round-trip through per-wave-private LDS
// (D-layout -> B-layout transform); intra-wave only => no __syncthreads needed
// after the initial tail-weight copy.
//
// MFMA 16x16x32 layouts (guide-verified m89/m120):
//   A[m][k]: m = lane&15, k = (lane>>4)*8 + j   (j=0..7, short8 frag)
//   B[k][n]: n = lane&15, k = (lane>>4)*8 + j
//   C/D:     col(n) = lane&15, row(m) = (lane>>4)*4 + reg

#define NEG_SLOPE 0.01f

typedef __attribute__((ext_vector_type(8))) short bf16x8;
typedef __attribute__((ext_vector_type(4))) float f32x4;

__device__ __forceinline__ float leaky(float v) { return v >= 0.f ? v : NEG_SLOPE * v; }

// round-to-nearest-even fp32 -> bf16 (bit pattern as short)
__device__ __forceinline__ short f2b(float f) {
    unsigned u = __float_as_uint(f);
    u += 0x7fffu + ((u >> 16) & 1u);
    return (short)(u >> 16);
}

__device__ __forceinline__ unsigned pk(float a, float b) {
    return (unsigned)(unsigned short)f2b(a) | ((unsigned)(unsigned short)f2b(b) << 16);
}

// load an A-frag (bf16) from an o-major fp32 weight matrix W[m][k], row length C
__device__ __forceinline__ bf16x8 loadA(const float* __restrict__ wsrc, int C, int m, int k) {
    const float* pr = wsrc + m * C + k;
    f32x4 lo = *(const f32x4*)pr;
    f32x4 hi = *(const f32x4*)(pr + 4);
    bf16x8 r;
    r[0] = f2b(lo[0]); r[1] = f2b(lo[1]); r[2] = f2b(lo[2]); r[3] = f2b(lo[3]);
    r[4] = f2b(hi[0]); r[5] = f2b(hi[1]); r[6] = f2b(hi[2]); r[7] = f2b(hi[3]);
    return r;
}

__global__ __launch_bounds__(256) void fused_mfma_kernel(
    const float* __restrict__ x,
    const float* __restrict__ w1, const float* __restrict__ w2,
    const float* __restrict__ w3, const float* __restrict__ w4,
    const float* __restrict__ w5, const float* __restrict__ w6,
    const float* __restrict__ w7, float* __restrict__ out) {
    constexpr int HW = 65536;  // 256*256

    // per-wave-private LDS slices (no inter-wave sharing => no barriers in main loop)
    __shared__ short lds_h1[4][16 * 72];  // [px 0..15][ch 0..63], stride 72 bf16 (144 B)
    __shared__ short lds_h2[4][16 * 40];  // [px 0..15][ch 0..31], stride 40 bf16 (80 B)
    __shared__ float lds_h3[4][64 * 17];  // [px 0..63][ch 0..15], stride 17 f32 (68 B)
    __shared__ float lds_tw[176];         // tail weights: w4[128] w5[32] w6[8] w7[2]

    const int tid = threadIdx.x;
    if (tid < 128)      lds_tw[tid] = w4[tid];
    else if (tid < 160) lds_tw[tid] = w5[tid - 128];
    else if (tid < 168) lds_tw[tid] = w6[tid - 160];
    else if (tid < 170) lds_tw[tid] = w7[tid - 168];
    __syncthreads();  // the only barrier: tail weights visible to all waves

    const int w    = tid >> 6;
    const int lane = tid & 63;
    const int p    = lane & 15;   // n (pixel) / m minor index
    const int q    = lane >> 4;   // quad

    const int px0   = blockIdx.x * 256 + w * 64;  // wave's 64 contiguous pixels
    const int batch = px0 >> 16;
    const int pin   = px0 & (HW - 1);
    const float* xb = x + (size_t)batch * 128 * HW;

    // ---- preload weight A-frags (identical across waves; tiny, L2-cached) ----
    bf16x8 a1[4][4];  // L1: M=64 (4 Mt), K=128 (4 Ks)
#pragma unroll
    for (int Mt = 0; Mt < 4; ++Mt)
#pragma unroll
        for (int Ks = 0; Ks < 4; ++Ks)
            a1[Mt][Ks] = loadA(w1, 128, Mt * 16 + p, Ks * 32 + q * 8);
    bf16x8 a2[2][2];  // L2: M=32, K=64
#pragma unroll
    for (int Mt = 0; Mt < 2; ++Mt)
#pragma unroll
        for (int Ks = 0; Ks < 2; ++Ks)
            a2[Mt][Ks] = loadA(w2, 64, Mt * 16 + p, Ks * 32 + q * 8);
    bf16x8 a3 = loadA(w3, 32, p, q * 8);  // L3: M=16, K=32

#pragma unroll
    for (int Nt = 0; Nt < 4; ++Nt) {
        const float* xp = xb + pin + Nt * 16 + p;

        // ---- L1 B-frags straight from global: lane(q,p) elem j = x[ch=Ks*32+q*8+j][pix] ----
        bf16x8 bx[4];
#pragma unroll
        for (int Ks = 0; Ks < 4; ++Ks) {
            float t[8];
#pragma unroll
            for (int j = 0; j < 8; ++j)
                t[j] = xp[(size_t)(Ks * 32 + q * 8 + j) * HW];
#pragma unroll
            for (int j = 0; j < 8; ++j) bx[Ks][j] = f2b(t[j]);
        }

        // ---- L1: 4 Mt x 4 Ks MFMAs ----
        f32x4 d1[4];
#pragma unroll
        for (int Mt = 0; Mt < 4; ++Mt) {
            f32x4 acc = {0.f, 0.f, 0.f, 0.f};
#pragma unroll
            for (int Ks = 0; Ks < 4; ++Ks)
                acc = __builtin_amdgcn_mfma_f32_16x16x32_bf16(a1[Mt][Ks], bx[Ks], acc, 0, 0, 0);
            d1[Mt] = acc;
        }

        // ---- leaky + bf16 -> LDS h1: lane writes ch = Mt*16+q*4+{0..3} at row p ----
        {
            short* h1w = &lds_h1[w][p * 72];
#pragma unroll
            for (int Mt = 0; Mt < 4; ++Mt) {
                uint2 v;
                v.x = pk(leaky(d1[Mt][0]), leaky(d1[Mt][1]));
                v.y = pk(leaky(d1[Mt][2]), leaky(d1[Mt][3]));
                *(uint2*)(h1w + Mt * 16 + q * 4) = v;  // 8B-aligned: 144p+32Mt+8q
            }
        }

        // ---- L2 B-frags from LDS (intra-wave dep; compiler inserts lgkmcnt wait) ----
        bf16x8 b2[2];
#pragma unroll
        for (int Ks = 0; Ks < 2; ++Ks)
            b2[Ks] = *(const bf16x8*)&lds_h1[w][p * 72 + Ks * 32 + q * 8];

        f32x4 d2[2];
#pragma unroll
        for (int Mt = 0; Mt < 2; ++Mt) {
            f32x4 acc = {0.f, 0.f, 0.f, 0.f};
#pragma unroll
            for (int Ks = 0; Ks < 2; ++Ks)
                acc = __builtin_amdgcn_mfma_f32_16x16x32_bf16(a2[Mt][Ks], b2[Ks], acc, 0, 0, 0);
            d2[Mt] = acc;
        }

        // ---- leaky + bf16 -> LDS h2 ----
        {
            short* h2w = &lds_h2[w][p * 40];
#pragma unroll
            for (int Mt = 0; Mt < 2; ++Mt) {
                uint2 v;
                v.x = pk(leaky(d2[Mt][0]), leaky(d2[Mt][1]));
                v.y = pk(leaky(d2[Mt][2]), leaky(d2[Mt][3]));
                *(uint2*)(h2w + Mt * 16 + q * 4) = v;
            }
        }

        // ---- L3: single MFMA (M=16, K=32) ----
        bf16x8 b3 = *(const bf16x8*)&lds_h2[w][p * 40 + q * 8];
        f32x4 zero = {0.f, 0.f, 0.f, 0.f};
        f32x4 d3 = __builtin_amdgcn_mfma_f32_16x16x32_bf16(a3, b3, zero, 0, 0, 0);

        // ---- h3 (fp32, leaky) -> LDS, row = Nt*16+p, ch = q*4+r ----
        {
            float* h3w = &lds_h3[w][(Nt * 16 + p) * 17 + q * 4];
            h3w[0] = leaky(d3[0]);
            h3w[1] = leaky(d3[1]);
            h3w[2] = leaky(d3[2]);
            h3w[3] = leaky(d3[3]);
        }
    }

    // ---- tail: 1 pixel per lane, L4-L7 in fp32 VALU, weights broadcast from LDS ----
    const float* h3r = &lds_h3[w][lane * 17];  // stride 17: banks 17*lane%32 conflict-free
    float h[16];
#pragma unroll
    for (int c = 0; c < 16; ++c) h[c] = h3r[c];

    float g4[8];
#pragma unroll
    for (int o = 0; o < 8; ++o) {
        float a = 0.f;
#pragma unroll
        for (int c = 0; c < 16; ++c) a = fmaf(lds_tw[o * 16 + c], h[c], a);
        g4[o] = leaky(a);
    }
    float g5[4];
#pragma unroll
    for (int o = 0; o < 4; ++o) {
        float a = 0.f;
#pragma unroll
        for (int c = 0; c < 8; ++c) a = fmaf(lds_tw[128 + o * 8 + c], g4[c], a);
        g5[o] = leaky(a);
    }
    float g6[2];
#pragma unroll
    for (int o = 0; o < 2; ++o) {
        float a = 0.f;
#pragma unroll
        for (int c = 0; c < 4; ++c) a = fmaf(lds_tw[160 + o * 4 + c], g5[c], a);
        g6[o] = leaky(a);
    }
    out[px0 + lane] = fmaf(lds_tw[168], g6[0], lds_tw[169] * g6[1]);
}

extern "C" void kernel_launch(void* const* d_in, const int* in_sizes, int n_in,
                              void* d_out, int out_size, void* d_ws, size_t ws_size,
                              hipStream_t stream) {
    const float* x  = (const float*)d_in[0];
    const float* w1 = (const float*)d_in[1];
    const float* w2 = (const float*)d_in[2];
    const float* w3 = (const float*)d_in[3];
    const float* w4 = (const float*)d_in[4];
    const float* w5 = (const float*)d_in[5];
    const float* w6 = (const float*)d_in[6];
    const float* w7 = (const float*)d_in[7];
    float* out = (float*)d_out;

    const int P = 8 * 256 * 256;  // 524288 pixels; block = 256 px (4 waves x 64)
    fused_mfma_kernel<<<P / 256, 256, 0, stream>>>(x, w1, w2, w3, w4, w5, w6, w7, out);
}

// Round 3
// 402.686 us; speedup vs baseline: 1.0920x; 1.0920x over previous
//
#include <hip/hip_runtime.h>

// Fused 7-layer 1x1-conv chain: L1-L3 via bf16 MFMA 16x16x32 (layouts verified in
// round 2), L4-L7 fp32 VALU tail. Round-3 change: x is staged global->LDS with
// __builtin_amdgcn_global_load_lds (16B/lane, double-buffered 32-ch K-chunks) so
// HBM concurrency comes from the async LDS queue instead of VGPR load targets.
// Block = 128 px (4 waves x 32 px); weights as bf16 A-frags in VGPRs (loaded once).
//
// MFMA 16x16x32 layouts: A[m][k]: m=lane&15, k=(lane>>4)*8+j
//                        B[k][n]: n=lane&15, k=(lane>>4)*8+j
//                        C/D: col=lane&15, row=(lane>>4)*4+reg

#define NEG_SLOPE 0.01f
constexpr int HW = 65536;  // 256*256

typedef __attribute__((ext_vector_type(8))) short bf16x8;
typedef __attribute__((ext_vector_type(4))) float f32x4;
typedef __attribute__((ext_vector_type(2))) float f32x2;

__device__ __forceinline__ float leaky(float v) { return v >= 0.f ? v : NEG_SLOPE * v; }

__device__ __forceinline__ short f2b(float f) {  // RNE fp32->bf16
    unsigned u = __float_as_uint(f);
    u += 0x7fffu + ((u >> 16) & 1u);
    return (short)(u >> 16);
}
__device__ __forceinline__ unsigned pk2(float a, float b) {
    return (unsigned)(unsigned short)f2b(a) | ((unsigned)(unsigned short)f2b(b) << 16);
}

// A-frag from o-major fp32 weight matrix W[m][k] (row length C); k 8-aligned
__device__ __forceinline__ bf16x8 loadA(const float* __restrict__ wsrc, int C, int m, int k) {
    f32x4 lo = *(const f32x4*)(wsrc + m * C + k);
    f32x4 hi = *(const f32x4*)(wsrc + m * C + k + 4);
    union { bf16x8 v; unsigned u[4]; } r;
    r.u[0] = pk2(lo[0], lo[1]); r.u[1] = pk2(lo[2], lo[3]);
    r.u[2] = pk2(hi[0], hi[1]); r.u[3] = pk2(hi[2], hi[3]);
    return r.v;
}

__device__ __forceinline__ void async_cp16(const float* g, float* l) {
    __builtin_amdgcn_global_load_lds((const __attribute__((address_space(1))) unsigned*)g,
                                     (__attribute__((address_space(3))) unsigned*)l,
                                     16, 0, 0);
}

__global__ __launch_bounds__(256, 2) void fused_staged_kernel(
    const float* __restrict__ x,
    const float* __restrict__ w1, const float* __restrict__ w2,
    const float* __restrict__ w3, const float* __restrict__ w4,
    const float* __restrict__ w5, const float* __restrict__ w6,
    const float* __restrict__ w7, float* __restrict__ out) {
    __shared__ float lds_x[2][32 * 128];            // K-chunk: 32 ch x 128 px fp32, dbuf
    __shared__ unsigned long long lds_un[4][544];   // per-wave 4352B: h1(68sh)/h2(36sh)/h3(18f) union
    __shared__ float lds_tw[176];                   // tail weights w4|w5|w6|w7

    const int tid = threadIdx.x;
    if (tid < 128)      lds_tw[tid] = w4[tid];
    else if (tid < 160) lds_tw[tid] = w5[tid - 128];
    else if (tid < 168) lds_tw[tid] = w6[tid - 160];
    else if (tid < 170) lds_tw[tid] = w7[tid - 168];

    const int w    = tid >> 6;
    const int lane = tid & 63;
    const int n    = lane & 15;   // frag row/col minor index
    const int q    = lane >> 4;   // quad
    const int half = lane >> 5;
    const int pl   = lane & 31;

    const int px0   = blockIdx.x * 128;  // block's 128 contiguous pixels (batch-uniform)
    const int batch = px0 >> 16;
    const int pin   = px0 & (HW - 1);
    const float* xg = x + (size_t)batch * 128 * HW + pin;

    // ---- stage chunk 0 (ch 0..31): 16 instr/block, each covers 2 channel rows ----
#pragma unroll
    for (int i = 0; i < 4; ++i) {
        int cp = w * 8 + 2 * i;                       // wave-uniform channel pair base
        const float* g = xg + (size_t)(cp + half) * HW + pl * 4;
        async_cp16(g, &lds_x[0][cp * 128]);           // lanes 0-31 -> row cp, 32-63 -> cp+1
    }

    // ---- weight A-frags into VGPRs (one-time; L2-hot after first blocks) ----
    bf16x8 a1[4][4];  // L1: M=64 (4 Mt) x K=128 (4 kc)
#pragma unroll
    for (int Mt = 0; Mt < 4; ++Mt)
#pragma unroll
        for (int kc = 0; kc < 4; ++kc)
            a1[Mt][kc] = loadA(w1, 128, Mt * 16 + n, kc * 32 + q * 8);
    bf16x8 a2[2][2];  // L2: M=32 x K=64
#pragma unroll
    for (int Mt = 0; Mt < 2; ++Mt)
#pragma unroll
        for (int kc = 0; kc < 2; ++kc)
            a2[Mt][kc] = loadA(w2, 64, Mt * 16 + n, kc * 32 + q * 8);
    bf16x8 a3 = loadA(w3, 32, n, q * 8);  // L3: M=16 x K=32

    __syncthreads();  // drains chunk-0 staging + tw writes

    // ---- L1 main loop: 4 K-chunks, double-buffered ----
    f32x4 acc1[4][2];
#pragma unroll
    for (int Mt = 0; Mt < 4; ++Mt)
#pragma unroll
        for (int Nt = 0; Nt < 2; ++Nt) acc1[Mt][Nt] = (f32x4){0.f, 0.f, 0.f, 0.f};

#pragma unroll
    for (int kc = 0; kc < 4; ++kc) {
        if (kc < 3) {  // prefetch next chunk into alternate buffer
#pragma unroll
            for (int i = 0; i < 4; ++i) {
                int cp = w * 8 + 2 * i;
                const float* g = xg + (size_t)((kc + 1) * 32 + cp + half) * HW + pl * 4;
                async_cp16(g, &lds_x[(kc + 1) & 1][cp * 128]);
            }
        }
        const float* xb = &lds_x[kc & 1][0];
#pragma unroll
        for (int Nt = 0; Nt < 2; ++Nt) {
            float t[8];
#pragma unroll
            for (int j = 0; j < 8; ++j)
                t[j] = xb[(q * 8 + j) * 128 + w * 32 + Nt * 16 + n];  // 8x ds_read_b32
            union { bf16x8 v; unsigned u[4]; } b;
            b.u[0] = pk2(t[0], t[1]); b.u[1] = pk2(t[2], t[3]);
            b.u[2] = pk2(t[4], t[5]); b.u[3] = pk2(t[6], t[7]);
#pragma unroll
            for (int Mt = 0; Mt < 4; ++Mt)
                acc1[Mt][Nt] = __builtin_amdgcn_mfma_f32_16x16x32_bf16(a1[Mt][kc], b.v, acc1[Mt][Nt], 0, 0, 0);
        }
        if (kc < 3) __syncthreads();  // drains prefetch before next compute
    }

    // ---- epilogue (all intra-wave; per-wave DS ops are in-order => no barriers) ----
    short* h1 = (short*)&lds_un[w][0];  // [32 px][64 ch] stride 68 shorts
#pragma unroll
    for (int Mt = 0; Mt < 4; ++Mt)
#pragma unroll
        for (int Nt = 0; Nt < 2; ++Nt) {
            int px = Nt * 16 + n;
            uint2 v;
            v.x = pk2(leaky(acc1[Mt][Nt][0]), leaky(acc1[Mt][Nt][1]));
            v.y = pk2(leaky(acc1[Mt][Nt][2]), leaky(acc1[Mt][Nt][3]));
            *(uint2*)(h1 + px * 68 + Mt * 16 + q * 4) = v;  // 8B-aligned
        }

    f32x4 acc2[2][2];
#pragma unroll
    for (int Mt = 0; Mt < 2; ++Mt)
#pragma unroll
        for (int Nt = 0; Nt < 2; ++Nt) acc2[Mt][Nt] = (f32x4){0.f, 0.f, 0.f, 0.f};
#pragma unroll
    for (int Nt = 0; Nt < 2; ++Nt)
#pragma unroll
        for (int kc = 0; kc < 2; ++kc) {
            int off = (Nt * 16 + n) * 68 + kc * 32 + q * 8;
            uint2 lo = *(const uint2*)(h1 + off);
            uint2 hi = *(const uint2*)(h1 + off + 4);
            union { bf16x8 v; unsigned u[4]; } b;
            b.u[0] = lo.x; b.u[1] = lo.y; b.u[2] = hi.x; b.u[3] = hi.y;
#pragma unroll
            for (int Mt = 0; Mt < 2; ++Mt)
                acc2[Mt][Nt] = __builtin_amdgcn_mfma_f32_16x16x32_bf16(a2[Mt][kc], b.v, acc2[Mt][Nt], 0, 0, 0);
        }

    short* h2 = (short*)&lds_un[w][0];  // [32 px][32 ch] stride 36 shorts (reuse; in-order DS)
#pragma unroll
    for (int Mt = 0; Mt < 2; ++Mt)
#pragma unroll
        for (int Nt = 0; Nt < 2; ++Nt) {
            int px = Nt * 16 + n;
            uint2 v;
            v.x = pk2(leaky(acc2[Mt][Nt][0]), leaky(acc2[Mt][Nt][1]));
            v.y = pk2(leaky(acc2[Mt][Nt][2]), leaky(acc2[Mt][Nt][3]));
            *(uint2*)(h2 + px * 36 + Mt * 16 + q * 4) = v;
        }

    f32x4 acc3[2];
#pragma unroll
    for (int Nt = 0; Nt < 2; ++Nt) {
        int off = (Nt * 16 + n) * 36 + q * 8;
        uint2 lo = *(const uint2*)(h2 + off);
        uint2 hi = *(const uint2*)(h2 + off + 4);
        union { bf16x8 v; unsigned u[4]; } b;
        b.u[0] = lo.x; b.u[1] = lo.y; b.u[2] = hi.x; b.u[3] = hi.y;
        f32x4 zero = {0.f, 0.f, 0.f, 0.f};
        acc3[Nt] = __builtin_amdgcn_mfma_f32_16x16x32_bf16(a3, b.v, zero, 0, 0, 0);
    }

    float* h3 = (float*)&lds_un[w][0];  // [32 px][16 ch] stride 18 floats
#pragma unroll
    for (int Nt = 0; Nt < 2; ++Nt) {
        int px = Nt * 16 + n;
        f32x2 va = {leaky(acc3[Nt][0]), leaky(acc3[Nt][1])};
        f32x2 vb = {leaky(acc3[Nt][2]), leaky(acc3[Nt][3])};
        *(f32x2*)(h3 + px * 18 + q * 4)     = va;
        *(f32x2*)(h3 + px * 18 + q * 4 + 2) = vb;
    }

    // ---- tail L4-L7, one px per lane (halves duplicate; lower half stores) ----
    float hh[16];
#pragma unroll
    for (int c = 0; c < 16; ++c) hh[c] = h3[pl * 18 + c];

    float g4[8];
#pragma unroll
    for (int o = 0; o < 8; ++o) {
        float a = 0.f;
#pragma unroll
        for (int c = 0; c < 16; ++c) a = fmaf(lds_tw[o * 16 + c], hh[c], a);
        g4[o] = leaky(a);
    }
    float g5[4];
#pragma unroll
    for (int o = 0; o < 4; ++o) {
        float a = 0.f;
#pragma unroll
        for (int c = 0; c < 8; ++c) a = fmaf(lds_tw[128 + o * 8 + c], g4[c], a);
        g5[o] = leaky(a);
    }
    float g6[2];
#pragma unroll
    for (int o = 0; o < 2; ++o) {
        float a = 0.f;
#pragma unroll
        for (int c = 0; c < 4; ++c) a = fmaf(lds_tw[160 + o * 4 + c], g5[c], a);
        g6[o] = leaky(a);
    }
    float res = fmaf(lds_tw[168], g6[0], lds_tw[169] * g6[1]);
    if (lane < 32) out[px0 + w * 32 + pl] = res;
}

extern "C" void kernel_launch(void* const* d_in, const int* in_sizes, int n_in,
                              void* d_out, int out_size, void* d_ws, size_t ws_size,
                              hipStream_t stream) {
    const float* x  = (const float*)d_in[0];
    const float* w1 = (const float*)d_in[1];
    const float* w2 = (const float*)d_in[2];
    const float* w3 = (const float*)d_in[3];
    const float* w4 = (const float*)d_in[4];
    const float* w5 = (const float*)d_in[5];
    const float* w6 = (const float*)d_in[6];
    const float* w7 = (const float*)d_in[7];
    float* out = (float*)d_out;

    const int P = 8 * 256 * 256;
    fused_staged_kernel<<<P / 128, 256, 0, stream>>>(x, w1, w2, w3, w4, w5, w6, w7, out);
}